// Round 3
// baseline (511.796 us; speedup 1.0000x reference)
//
#include <hip/hip_runtime.h>

#define HW 2304
#define W48 48
#define RSPW 59            // recSP width in float4: col k holds rec[(k-2)%48]
#define RS_STRIDE 48       // Rs row stride (floats)
#define RS_ROWS 52         // rows 0..51 = R((r-2) mod 48)
#define RS_SIZE (RS_ROWS * RS_STRIDE)

// ---------------------------------------------------------------------------
// prep: build rec_ext (float4: c0,c1,c2,walls) for all 16 timesteps,
//       build cur0 (frame 0 + walls), copy frame 0 (3ch) to d_out.
// ---------------------------------------------------------------------------
__global__ __launch_bounds__(256) void prep_kernel(
    const float* __restrict__ x, const float* __restrict__ rec,
    const float* __restrict__ walls,
    float4* __restrict__ rec4, float4* __restrict__ cur0,
    float* __restrict__ dout)
{
    int id = blockIdx.x * 256 + threadIdx.x;
    if (id < 16 * HW) {
        int t = id / HW, p = id % HW;
        rec4[id] = make_float4(rec[(t * 3 + 0) * HW + p],
                               rec[(t * 3 + 1) * HW + p],
                               rec[(t * 3 + 2) * HW + p],
                               walls[p]);
    }
    if (id < HW) {
        cur0[id] = make_float4(x[0 * HW + id], x[1 * HW + id], x[2 * HW + id],
                               walls[id]);
    }
    if (id < 3 * HW) {
        dout[id] = x[id];  // frame 0, channels 0..2
    }
}

// ---------------------------------------------------------------------------
// dist v3: block=(t,sy), 720 blocks x 384 threads (6 waves).
// AB ownership: row yA=tid>>3, x0=6*(tid&7): 6 outputs R(yA, x0..x0+5).
//   rec window (10 float4) lives in a 12-slot register ring sliding 1/sx
//   -> only one ds_read_b128 per thread per sx.
// C ownership: col xC=tid%48, strip y0=6*(tid/48): 6 outputs D(y0..y0+5, xC).
// Rs double-buffered -> exactly one barrier per sx.
// F/R/D expressions and summation order are bit-identical to round 2.
// ---------------------------------------------------------------------------
__global__ __launch_bounds__(384, 3) void dist_kernel(
    const float4* __restrict__ rec4, const float4* __restrict__ cur4,
    unsigned long long* __restrict__ best)
{
    __shared__ float4 recSP[W48 * RSPW];   // 45312 B
    __shared__ float  Rs[2 * RS_SIZE];     // 19968 B

    const int tid = threadIdx.x;
    const int b   = blockIdx.x;
    const int sy  = b % W48;
    const int t   = b / W48;

    // AB ownership
    const int yA = tid >> 3;          // 0..47
    const int cA = tid & 7;           // 0..7
    const int x0 = 6 * cA;            // 0..42
    int ryA = yA + sy; if (ryA >= W48) ryA -= W48;

    // C ownership
    const int xC = tid % W48;
    const int y0 = 6 * (tid / W48);

    unsigned int mb[6];
#pragma unroll
    for (int i = 0; i < 6; i++) {
        int ry = y0 + i + sy; if (ry >= W48) ry -= W48;
        mb[i] = (unsigned int)(t * HW + ry * W48);
    }

    // cur window (fixed per thread): x' = x0-2+j, j=0..9
    float4 curW[10];
#pragma unroll
    for (int j = 0; j < 10; j++) {
        int xx = x0 - 2 + j;
        if (xx < 0) xx += W48;
        if (xx >= W48) xx -= W48;
        curW[j] = cur4[yA * W48 + xx];
    }

    // stage recSP[y][k] = rec[t][y][(k-2)%48], k = 0..58
#pragma unroll
    for (int j = 0; j < 8; j++) {
        int k = 8 * cA + j;
        if (k < RSPW) {
            int xx = k - 2;
            if (xx < 0) xx += W48;
            if (xx >= W48) xx -= W48;
            recSP[yA * RSPW + k] = rec4[t * HW + yA * W48 + xx];
        }
    }

    unsigned long long bst[6];
#pragma unroll
    for (int i = 0; i < 6; i++) bst[i] = ~0ULL;

    __syncthreads();

    // register ring: slots (sx+j)%12, j=0..9 = rec cols (x0-2+sx+j)%48
    int r0 = x0 - 2; if (r0 < 0) r0 += W48;   // = (x0-2+sx)%48 at sx=0
    float4 wR[12];
#pragma unroll
    for (int j = 0; j < 10; j++)
        wR[j] = recSP[ryA * RSPW + r0 + 2 + j];

    float* RsB0 = &Rs[0];
    float* RsB1 = &Rs[RS_SIZE];
    int rx = xC;                               // = (xC+sx)%48

    for (int so = 0; so < 4; so++) {
#pragma unroll
        for (int su = 0; su < 12; su++) {
            float* RsB = (su & 1) ? RsB1 : RsB0;
            // ---- AB: F from curW x ring, row box-sums ----
            float F[10];
#pragma unroll
            for (int j = 0; j < 10; j++) {
                float4 w = wR[(su + j) % 12];
                float d0 = curW[j].x - w.x;
                float d1 = curW[j].y - w.y;
                float d2 = curW[j].z - w.z;
                float d3 = curW[j].w - w.w;
                F[j] = d0 * d0 + d1 * d1 + d2 * d2 + d3 * d3;
            }
            float R0 = F[0] + F[1] + F[2] + F[3] + F[4];
            float R1 = F[1] + F[2] + F[3] + F[4] + F[5];
            float R2 = F[2] + F[3] + F[4] + F[5] + F[6];
            float R3 = F[3] + F[4] + F[5] + F[6] + F[7];
            float R4 = F[4] + F[5] + F[6] + F[7] + F[8];
            float R5 = F[5] + F[6] + F[7] + F[8] + F[9];
            {
                float* rw = &RsB[(yA + 2) * RS_STRIDE + x0];
                *(float2*)&rw[0] = make_float2(R0, R1);
                *(float2*)&rw[2] = make_float2(R2, R3);
                *(float2*)&rw[4] = make_float2(R4, R5);
            }
            if (yA < 2) {          // duplicate to rows 50,51 (wrap top)
                float* rw = &RsB[(yA + 50) * RS_STRIDE + x0];
                *(float2*)&rw[0] = make_float2(R0, R1);
                *(float2*)&rw[2] = make_float2(R2, R3);
                *(float2*)&rw[4] = make_float2(R4, R5);
            }
            if (yA >= 46) {        // duplicate to rows 0,1 (wrap bottom)
                float* rw = &RsB[(yA - 46) * RS_STRIDE + x0];
                *(float2*)&rw[0] = make_float2(R0, R1);
                *(float2*)&rw[2] = make_float2(R2, R3);
                *(float2*)&rw[4] = make_float2(R4, R5);
            }
            // prefetch next window element into retiring slot (overlaps barrier)
            r0++; if (r0 >= W48) r0 -= W48;
            wR[(su + 10) % 12] = recSP[ryA * RSPW + r0 + 11];

            __syncthreads();

            // ---- C: column box-sums + packed-min ----
            {
                const float* rp = &RsB[y0 * RS_STRIDE + xC];
                float rv[10];
#pragma unroll
                for (int j = 0; j < 10; j++) rv[j] = rp[j * RS_STRIDE];
#pragma unroll
                for (int i = 0; i < 6; i++) {
                    float d = rv[i] + rv[i + 1] + rv[i + 2] + rv[i + 3] +
                              rv[i + 4];
                    unsigned long long pk =
                        ((unsigned long long)__float_as_uint(d) << 32) |
                        (mb[i] + rx);
                    bst[i] = pk < bst[i] ? pk : bst[i];
                }
            }
            rx++; if (rx >= W48) rx -= W48;
        }
    }

#pragma unroll
    for (int i = 0; i < 6; i++)
        atomicMin(&best[(y0 + i) * W48 + xC], bst[i]);
}

// ---------------------------------------------------------------------------
// gather: decode best[p]; gather center pixel of (t+1) patch; write output
// frame + next carry + per-element sq-error.
// ---------------------------------------------------------------------------
__global__ __launch_bounds__(256) void gather_kernel(
    const unsigned long long* __restrict__ best,
    const float4* __restrict__ rec4, const float* __restrict__ x,
    const float* __restrict__ walls,
    float4* __restrict__ curnext, float* __restrict__ dout,
    float* __restrict__ err, int step)
{
    int p = blockIdx.x * 256 + threadIdx.x;
    if (p >= HW) return;
    unsigned int m = (unsigned int)best[p];
    int t = m / HW, q = m % HW;
    float4 v = rec4[(t + 1) * HW + q];
    curnext[p] = v;
    dout[(step + 1) * 3 * HW + 0 * HW + p] = v.x;
    dout[(step + 1) * 3 * HW + 1 * HW + p] = v.y;
    dout[(step + 1) * 3 * HW + 2 * HW + p] = v.z;
    float t0 = x[((step + 1) * 3 + 0) * HW + p];
    float t1 = x[((step + 1) * 3 + 1) * HW + p];
    float t2 = x[((step + 1) * 3 + 2) * HW + p];
    float t3 = walls[p];
    float e = (v.x - t0) * (v.x - t0) + (v.y - t1) * (v.y - t1) +
              (v.z - t2) * (v.z - t2) + (v.w - t3) * (v.w - t3);
    err[step * HW + p] = e;
}

// ---------------------------------------------------------------------------
// loss: deterministic reduction; loss = total / 18432.
// ---------------------------------------------------------------------------
__global__ __launch_bounds__(256) void loss_kernel(
    const float* __restrict__ err, float* __restrict__ dout)
{
    __shared__ float ssum[256];
    float s = 0.f;
    for (int i = threadIdx.x; i < 2 * HW; i += 256) s += err[i];
    ssum[threadIdx.x] = s;
    __syncthreads();
    for (int w = 128; w > 0; w >>= 1) {
        if (threadIdx.x < w) ssum[threadIdx.x] += ssum[threadIdx.x + w];
        __syncthreads();
    }
    if (threadIdx.x == 0) dout[9 * HW] = ssum[0] / 18432.0f;
}

extern "C" void kernel_launch(void* const* d_in, const int* in_sizes, int n_in,
                              void* d_out, int out_size, void* d_ws,
                              size_t ws_size, hipStream_t stream)
{
    const float* x     = (const float*)d_in[0];
    const float* rec   = (const float*)d_in[1];
    const float* walls = (const float*)d_in[2];
    float* dout = (float*)d_out;

    char* ws = (char*)d_ws;
    float4* rec4 = (float4*)ws;                               // 589824 B
    float4* curb = (float4*)(ws + 589824);                    // 110592 B
    float*  err  = (float*)(ws + 589824 + 110592);            //  18432 B
    unsigned long long* best =
        (unsigned long long*)(ws + 589824 + 110592 + 18432);  //  18432 B

    prep_kernel<<<144, 256, 0, stream>>>(x, rec, walls, rec4, curb, dout);
    for (int step = 0; step < 2; step++) {
        hipMemsetAsync(best, 0xFF, (size_t)HW * 8, stream);
        dist_kernel<<<15 * W48, 384, 0, stream>>>(rec4, curb + step * HW, best);
        gather_kernel<<<9, 256, 0, stream>>>(best, rec4, x, walls,
                                             curb + (step + 1) * HW, dout, err,
                                             step);
    }
    loss_kernel<<<1, 256, 0, stream>>>(err, dout);
}

// Round 4
// 216.877 us; speedup vs baseline: 2.3598x; 2.3598x over previous
//
#include <hip/hip_runtime.h>

#define HW 2304
#define W48 48
#define RSPW4 49           // recSP stride in float4 (odd -> spreads bank groups)
#define RS_STRIDE 50       // Rs row stride in floats (even: float2-aligned rows)
#define RS_ROWS 52         // rows 0..51 hold R((r-2) mod 48)
#define RS_SIZE (RS_ROWS * RS_STRIDE)

// ---------------------------------------------------------------------------
// prep: build rec_ext (float4: c0,c1,c2,walls) for all 16 timesteps,
//       build cur0 (frame 0 + walls), copy frame 0 (3ch) to d_out.
// ---------------------------------------------------------------------------
__global__ __launch_bounds__(256) void prep_kernel(
    const float* __restrict__ x, const float* __restrict__ rec,
    const float* __restrict__ walls,
    float4* __restrict__ rec4, float4* __restrict__ cur0,
    float* __restrict__ dout)
{
    int id = blockIdx.x * 256 + threadIdx.x;
    if (id < 16 * HW) {
        int t = id / HW, p = id % HW;
        rec4[id] = make_float4(rec[(t * 3 + 0) * HW + p],
                               rec[(t * 3 + 1) * HW + p],
                               rec[(t * 3 + 2) * HW + p],
                               walls[p]);
    }
    if (id < HW) {
        cur0[id] = make_float4(x[0 * HW + id], x[1 * HW + id], x[2 * HW + id],
                               walls[id]);
    }
    if (id < 3 * HW) {
        dout[id] = x[id];  // frame 0, channels 0..2
    }
}

// ---------------------------------------------------------------------------
// dist v4: block=(t,sy), 720 blocks x 384 threads (6 waves).
// AB ownership: row yA=tid>>3, x0=6*(tid&7): 6 outputs R(yA, x0..x0+5).
//   rec window lives in SIX NAMED registers w0..w5 stepped by a macro stamped
//   with literal slot names (guaranteed register residency, rule #20).
//   F-halo (x0-2,x0-1,x0+6,x0+7) via ds_bpermute from row neighbors (row of 8
//   lanes is wave-internal). One ds_read_b128 ring refill per thread per sx.
// C ownership: col xC=tid%48, strip y0=6*(tid/48): 6 outputs D(y0..y0+5, xC).
// Rs double-buffered -> exactly one barrier per sx.
// F/R/D expressions and summation order bit-identical to round 2 (passed).
// ---------------------------------------------------------------------------
__global__ __launch_bounds__(384, 2) void dist_kernel(
    const float4* __restrict__ rec4, const float4* __restrict__ cur4,
    unsigned long long* __restrict__ best)
{
    __shared__ float4 recSP[W48 * RSPW4];   // 37632 B
    __shared__ float  Rs[2 * RS_SIZE];      // 20800 B

    const int tid = threadIdx.x;
    const int b   = blockIdx.x;
    const int sy  = b % W48;
    const int t   = b / W48;

    // AB ownership
    const int yA = tid >> 3;          // 0..47
    const int cA = tid & 7;           // 0..7
    const int x0 = 6 * cA;            // 0..42
    int ryA = yA + sy; if (ryA >= W48) ryA -= W48;

    // C ownership
    const int xC = tid % W48;
    const int y0 = 6 * (tid / W48);

    // bpermute byte-addresses: circular left/right neighbor within row-of-8
    const int lane  = tid & 63;
    const int addrL = ((lane & ~7) | ((cA + 7) & 7)) << 2;
    const int addrR = ((lane & ~7) | ((cA + 1) & 7)) << 2;

    unsigned int mb[6];
#pragma unroll
    for (int i = 0; i < 6; i++) {
        int ry = y0 + i + sy; if (ry >= W48) ry -= W48;
        mb[i] = (unsigned int)(t * HW + ry * W48);
    }

    // fixed cur window: cw_j = cur(yA, x0+j)   (x0+5 <= 47, no wrap)
    const float4 cw0 = cur4[yA * W48 + x0 + 0];
    const float4 cw1 = cur4[yA * W48 + x0 + 1];
    const float4 cw2 = cur4[yA * W48 + x0 + 2];
    const float4 cw3 = cur4[yA * W48 + x0 + 3];
    const float4 cw4 = cur4[yA * W48 + x0 + 4];
    const float4 cw5 = cur4[yA * W48 + x0 + 5];

    // stage recSP[y][k] = rec[t][y][k]
#pragma unroll
    for (int j = 0; j < 6; j++)
        recSP[yA * RSPW4 + x0 + j] = rec4[t * HW + yA * W48 + x0 + j];

    unsigned long long bst[6];
#pragma unroll
    for (int i = 0; i < 6; i++) bst[i] = ~0ULL;

    __syncthreads();

    // ring init: w_j = rec(ryA, x0+j)  (slot j holds col (x0+sx+j)%48)
    float4 w0 = recSP[ryA * RSPW4 + x0 + 0];
    float4 w1 = recSP[ryA * RSPW4 + x0 + 1];
    float4 w2 = recSP[ryA * RSPW4 + x0 + 2];
    float4 w3 = recSP[ryA * RSPW4 + x0 + 3];
    float4 w4 = recSP[ryA * RSPW4 + x0 + 4];
    float4 w5 = recSP[ryA * RSPW4 + x0 + 5];

    int nx = x0 + 6; if (nx >= W48) nx -= W48;  // next ring col to load
    int rx = xC;                                 // candidate col (xC+sx)%48

#define DIFF(D, C, Wv) do {                                                 \
        float d0 = (C).x - (Wv).x, d1 = (C).y - (Wv).y,                     \
              d2 = (C).z - (Wv).z, d3 = (C).w - (Wv).w;                     \
        D = d0 * d0 + d1 * d1 + d2 * d2 + d3 * d3;                          \
    } while (0)

#define STEP(P, S0, S1, S2, S3, S4, S5) do {                                \
        float F0, F1, F2, F3, F4, F5;                                       \
        DIFF(F0, cw0, S0); DIFF(F1, cw1, S1); DIFF(F2, cw2, S2);            \
        DIFF(F3, cw3, S3); DIFF(F4, cw4, S4); DIFF(F5, cw5, S5);            \
        float Fm2 = __int_as_float(                                         \
            __builtin_amdgcn_ds_bpermute(addrL, __float_as_int(F4)));       \
        float Fm1 = __int_as_float(                                         \
            __builtin_amdgcn_ds_bpermute(addrL, __float_as_int(F5)));       \
        float F6  = __int_as_float(                                         \
            __builtin_amdgcn_ds_bpermute(addrR, __float_as_int(F0)));       \
        float F7  = __int_as_float(                                         \
            __builtin_amdgcn_ds_bpermute(addrR, __float_as_int(F1)));       \
        float R0 = Fm2 + Fm1 + F0 + F1 + F2;                                \
        float R1 = Fm1 + F0 + F1 + F2 + F3;                                 \
        float R2 = F0 + F1 + F2 + F3 + F4;                                  \
        float R3 = F1 + F2 + F3 + F4 + F5;                                  \
        float R4 = F2 + F3 + F4 + F5 + F6;                                  \
        float R5 = F3 + F4 + F5 + F6 + F7;                                  \
        float* RsB = &Rs[(P) * RS_SIZE];                                    \
        {                                                                   \
            float* rw = &RsB[(yA + 2) * RS_STRIDE + x0];                    \
            *(float2*)&rw[0] = make_float2(R0, R1);                         \
            *(float2*)&rw[2] = make_float2(R2, R3);                         \
            *(float2*)&rw[4] = make_float2(R4, R5);                         \
        }                                                                   \
        if (yA < 2) {                                                       \
            float* rw = &RsB[(yA + 50) * RS_STRIDE + x0];                   \
            *(float2*)&rw[0] = make_float2(R0, R1);                         \
            *(float2*)&rw[2] = make_float2(R2, R3);                         \
            *(float2*)&rw[4] = make_float2(R4, R5);                         \
        }                                                                   \
        if (yA >= 46) {                                                     \
            float* rw = &RsB[(yA - 46) * RS_STRIDE + x0];                   \
            *(float2*)&rw[0] = make_float2(R0, R1);                         \
            *(float2*)&rw[2] = make_float2(R2, R3);                         \
            *(float2*)&rw[4] = make_float2(R4, R5);                         \
        }                                                                   \
        S0 = recSP[ryA * RSPW4 + nx];   /* refill retiring slot */          \
        nx++; if (nx >= W48) nx -= W48;                                     \
        __syncthreads();                                                    \
        {                                                                   \
            const float* rp = &RsB[y0 * RS_STRIDE + xC];                    \
            float rv[10];                                                   \
            _Pragma("unroll")                                               \
            for (int j = 0; j < 10; j++) rv[j] = rp[j * RS_STRIDE];         \
            _Pragma("unroll")                                               \
            for (int i = 0; i < 6; i++) {                                   \
                float d = rv[i] + rv[i + 1] + rv[i + 2] + rv[i + 3] +       \
                          rv[i + 4];                                        \
                unsigned long long pk =                                     \
                    ((unsigned long long)__float_as_uint(d) << 32) |        \
                    (mb[i] + rx);                                           \
                bst[i] = pk < bst[i] ? pk : bst[i];                         \
            }                                                               \
        }                                                                   \
        rx++; if (rx >= W48) rx -= W48;                                     \
    } while (0)

    for (int so = 0; so < 8; so++) {
        STEP(0, w0, w1, w2, w3, w4, w5);
        STEP(1, w1, w2, w3, w4, w5, w0);
        STEP(0, w2, w3, w4, w5, w0, w1);
        STEP(1, w3, w4, w5, w0, w1, w2);
        STEP(0, w4, w5, w0, w1, w2, w3);
        STEP(1, w5, w0, w1, w2, w3, w4);
    }
#undef STEP
#undef DIFF

#pragma unroll
    for (int i = 0; i < 6; i++)
        atomicMin(&best[(y0 + i) * W48 + xC], bst[i]);
}

// ---------------------------------------------------------------------------
// gather: decode best[p]; gather center pixel of (t+1) patch; write output
// frame + next carry + per-element sq-error.
// ---------------------------------------------------------------------------
__global__ __launch_bounds__(256) void gather_kernel(
    const unsigned long long* __restrict__ best,
    const float4* __restrict__ rec4, const float* __restrict__ x,
    const float* __restrict__ walls,
    float4* __restrict__ curnext, float* __restrict__ dout,
    float* __restrict__ err, int step)
{
    int p = blockIdx.x * 256 + threadIdx.x;
    if (p >= HW) return;
    unsigned int m = (unsigned int)best[p];
    int t = m / HW, q = m % HW;
    float4 v = rec4[(t + 1) * HW + q];
    curnext[p] = v;
    dout[(step + 1) * 3 * HW + 0 * HW + p] = v.x;
    dout[(step + 1) * 3 * HW + 1 * HW + p] = v.y;
    dout[(step + 1) * 3 * HW + 2 * HW + p] = v.z;
    float t0 = x[((step + 1) * 3 + 0) * HW + p];
    float t1 = x[((step + 1) * 3 + 1) * HW + p];
    float t2 = x[((step + 1) * 3 + 2) * HW + p];
    float t3 = walls[p];
    float e = (v.x - t0) * (v.x - t0) + (v.y - t1) * (v.y - t1) +
              (v.z - t2) * (v.z - t2) + (v.w - t3) * (v.w - t3);
    err[step * HW + p] = e;
}

// ---------------------------------------------------------------------------
// loss: deterministic reduction; loss = total / 18432.
// ---------------------------------------------------------------------------
__global__ __launch_bounds__(256) void loss_kernel(
    const float* __restrict__ err, float* __restrict__ dout)
{
    __shared__ float ssum[256];
    float s = 0.f;
    for (int i = threadIdx.x; i < 2 * HW; i += 256) s += err[i];
    ssum[threadIdx.x] = s;
    __syncthreads();
    for (int w = 128; w > 0; w >>= 1) {
        if (threadIdx.x < w) ssum[threadIdx.x] += ssum[threadIdx.x + w];
        __syncthreads();
    }
    if (threadIdx.x == 0) dout[9 * HW] = ssum[0] / 18432.0f;
}

extern "C" void kernel_launch(void* const* d_in, const int* in_sizes, int n_in,
                              void* d_out, int out_size, void* d_ws,
                              size_t ws_size, hipStream_t stream)
{
    const float* x     = (const float*)d_in[0];
    const float* rec   = (const float*)d_in[1];
    const float* walls = (const float*)d_in[2];
    float* dout = (float*)d_out;

    char* ws = (char*)d_ws;
    float4* rec4 = (float4*)ws;                               // 589824 B
    float4* curb = (float4*)(ws + 589824);                    // 110592 B
    float*  err  = (float*)(ws + 589824 + 110592);            //  18432 B
    unsigned long long* best =
        (unsigned long long*)(ws + 589824 + 110592 + 18432);  //  18432 B

    prep_kernel<<<144, 256, 0, stream>>>(x, rec, walls, rec4, curb, dout);
    for (int step = 0; step < 2; step++) {
        hipMemsetAsync(best, 0xFF, (size_t)HW * 8, stream);
        dist_kernel<<<15 * W48, 384, 0, stream>>>(rec4, curb + step * HW, best);
        gather_kernel<<<9, 256, 0, stream>>>(best, rec4, x, walls,
                                             curb + (step + 1) * HW, dout, err,
                                             step);
    }
    loss_kernel<<<1, 256, 0, stream>>>(err, dout);
}

// Round 5
// 185.625 us; speedup vs baseline: 2.7571x; 1.1684x over previous
//
#include <hip/hip_runtime.h>

#define HW 2304
#define W48 48
#define RS_STRIDE 50       // Rs row stride in floats
#define RS_ROWS 52         // rows 0..51 hold R((r-2) mod 48)
#define RS_SIZE (RS_ROWS * RS_STRIDE)

// ---------------------------------------------------------------------------
// prep: build rec_ext (float4: c0,c1,c2,walls) for all 16 timesteps,
//       build cur0 (frame 0 + walls), copy frame 0 (3ch) to d_out.
// ---------------------------------------------------------------------------
__global__ __launch_bounds__(256) void prep_kernel(
    const float* __restrict__ x, const float* __restrict__ rec,
    const float* __restrict__ walls,
    float4* __restrict__ rec4, float4* __restrict__ cur0,
    float* __restrict__ dout)
{
    int id = blockIdx.x * 256 + threadIdx.x;
    if (id < 16 * HW) {
        int t = id / HW, p = id % HW;
        rec4[id] = make_float4(rec[(t * 3 + 0) * HW + p],
                               rec[(t * 3 + 1) * HW + p],
                               rec[(t * 3 + 2) * HW + p],
                               walls[p]);
    }
    if (id < HW) {
        cur0[id] = make_float4(x[0 * HW + id], x[1 * HW + id], x[2 * HW + id],
                               walls[id]);
    }
    if (id < 3 * HW) {
        dout[id] = x[id];  // frame 0, channels 0..2
    }
}

// ---------------------------------------------------------------------------
// dist v5: block=(t,sy), 720 blocks x 384 threads (6 waves).
// LDS holds ONLY the double-buffered Rs exchange (20.8 KB) -> ~3 blocks/CU
// resident (v4's 58.9 KB recSP limited residency to 1 block -> latency-bound).
// rec rows are read from global (L2-resident, 576 KB) into an 8-slot NAMED
// register ring (s0..s7), refilled 2 cols per 2 sx one step ahead of use.
// F-halo via ds_bpermute from row-of-8 neighbors (wave-internal).
// F/R/D expressions and summation order bit-identical to round 4 (passed).
// ---------------------------------------------------------------------------
__global__ __launch_bounds__(384, 4) void dist_kernel(
    const float4* __restrict__ rec4, const float4* __restrict__ cur4,
    unsigned long long* __restrict__ best)
{
    __shared__ float Rs[2 * RS_SIZE];      // 20800 B

    const int tid = threadIdx.x;
    const int b   = blockIdx.x;
    const int sy  = b % W48;
    const int t   = b / W48;

    // AB ownership
    const int yA = tid >> 3;          // 0..47
    const int cA = tid & 7;           // 0..7
    const int x0 = 6 * cA;            // 0..42
    int ryA = yA + sy; if (ryA >= W48) ryA -= W48;

    // C ownership
    const int xC = tid % W48;
    const int y0 = 6 * (tid / W48);

    // bpermute byte-addresses: circular left/right neighbor within row-of-8
    const int lane  = tid & 63;
    const int addrL = ((lane & ~7) | ((cA + 7) & 7)) << 2;
    const int addrR = ((lane & ~7) | ((cA + 1) & 7)) << 2;

    unsigned int mb[6];
#pragma unroll
    for (int i = 0; i < 6; i++) {
        int ry = y0 + i + sy; if (ry >= W48) ry -= W48;
        mb[i] = (unsigned int)(t * HW + ry * W48);
    }

    // fixed cur window: cw_j = cur(yA, x0+j)   (x0+5 <= 47, no wrap)
    const float4* curRow = cur4 + yA * W48 + x0;
    const float4 cw0 = curRow[0];
    const float4 cw1 = curRow[1];
    const float4 cw2 = curRow[2];
    const float4 cw3 = curRow[3];
    const float4 cw4 = curRow[4];
    const float4 cw5 = curRow[5];

    // rec row base for this thread (L2-resident)
    const float4* recRow = rec4 + t * HW + ryA * W48;

    // ring init: slot j holds rec col (x0+sx+j)%48; at sx=0 -> x0+j (no wrap)
    float4 s0 = recRow[x0 + 0];
    float4 s1 = recRow[x0 + 1];
    float4 s2 = recRow[x0 + 2];
    float4 s3 = recRow[x0 + 3];
    float4 s4 = recRow[x0 + 4];
    float4 s5 = recRow[x0 + 5];
    float4 s6, s7;

    int nc = x0 + 6; if (nc >= W48) nc -= W48;  // next col to fetch
    int rx = xC;                                 // candidate col (xC+sx)%48

    unsigned long long bst[6];
#pragma unroll
    for (int i = 0; i < 6; i++) bst[i] = ~0ULL;

#define BURST(L0, L1) do {                                                  \
        int c0_ = nc;                                                       \
        int c1_ = nc + 1; if (c1_ >= W48) c1_ -= W48;                       \
        L0 = recRow[c0_];                                                   \
        L1 = recRow[c1_];                                                   \
        nc += 2; if (nc >= W48) nc -= W48;                                  \
    } while (0)

#define DIFF(D, C, Wv) do {                                                 \
        float d0 = (C).x - (Wv).x, d1 = (C).y - (Wv).y,                     \
              d2 = (C).z - (Wv).z, d3 = (C).w - (Wv).w;                     \
        D = d0 * d0 + d1 * d1 + d2 * d2 + d3 * d3;                          \
    } while (0)

#define STEP(P, S0, S1, S2, S3, S4, S5) do {                                \
        float F0, F1, F2, F3, F4, F5;                                       \
        DIFF(F0, cw0, S0); DIFF(F1, cw1, S1); DIFF(F2, cw2, S2);            \
        DIFF(F3, cw3, S3); DIFF(F4, cw4, S4); DIFF(F5, cw5, S5);            \
        float Fm2 = __int_as_float(                                         \
            __builtin_amdgcn_ds_bpermute(addrL, __float_as_int(F4)));       \
        float Fm1 = __int_as_float(                                         \
            __builtin_amdgcn_ds_bpermute(addrL, __float_as_int(F5)));       \
        float F6  = __int_as_float(                                         \
            __builtin_amdgcn_ds_bpermute(addrR, __float_as_int(F0)));       \
        float F7  = __int_as_float(                                         \
            __builtin_amdgcn_ds_bpermute(addrR, __float_as_int(F1)));       \
        float R0 = Fm2 + Fm1 + F0 + F1 + F2;                                \
        float R1 = Fm1 + F0 + F1 + F2 + F3;                                 \
        float R2 = F0 + F1 + F2 + F3 + F4;                                  \
        float R3 = F1 + F2 + F3 + F4 + F5;                                  \
        float R4 = F2 + F3 + F4 + F5 + F6;                                  \
        float R5 = F3 + F4 + F5 + F6 + F7;                                  \
        float* RsB = &Rs[(P) * RS_SIZE];                                    \
        {                                                                   \
            float* rw = &RsB[(yA + 2) * RS_STRIDE + x0];                    \
            *(float2*)&rw[0] = make_float2(R0, R1);                         \
            *(float2*)&rw[2] = make_float2(R2, R3);                         \
            *(float2*)&rw[4] = make_float2(R4, R5);                         \
        }                                                                   \
        if (yA < 2) {                                                       \
            float* rw = &RsB[(yA + 50) * RS_STRIDE + x0];                   \
            *(float2*)&rw[0] = make_float2(R0, R1);                         \
            *(float2*)&rw[2] = make_float2(R2, R3);                         \
            *(float2*)&rw[4] = make_float2(R4, R5);                         \
        }                                                                   \
        if (yA >= 46) {                                                     \
            float* rw = &RsB[(yA - 46) * RS_STRIDE + x0];                   \
            *(float2*)&rw[0] = make_float2(R0, R1);                         \
            *(float2*)&rw[2] = make_float2(R2, R3);                         \
            *(float2*)&rw[4] = make_float2(R4, R5);                         \
        }                                                                   \
        __syncthreads();                                                    \
        {                                                                   \
            const float* rp = &RsB[y0 * RS_STRIDE + xC];                    \
            float rv[10];                                                   \
            _Pragma("unroll")                                               \
            for (int j = 0; j < 10; j++) rv[j] = rp[j * RS_STRIDE];         \
            _Pragma("unroll")                                               \
            for (int i = 0; i < 6; i++) {                                   \
                float d = rv[i] + rv[i + 1] + rv[i + 2] + rv[i + 3] +       \
                          rv[i + 4];                                        \
                unsigned long long pk =                                     \
                    ((unsigned long long)__float_as_uint(d) << 32) |        \
                    (mb[i] + rx);                                           \
                bst[i] = pk < bst[i] ? pk : bst[i];                         \
            }                                                               \
        }                                                                   \
        rx++; if (rx >= W48) rx -= W48;                                     \
    } while (0)

    for (int so = 0; so < 6; so++) {
        BURST(s6, s7);                          // cols +6,+7 (used u=1,2)
        STEP(0, s0, s1, s2, s3, s4, s5);        // u=0
        STEP(1, s1, s2, s3, s4, s5, s6);        // u=1
        BURST(s0, s1);                          // cols +8,+9 (used u=3,4)
        STEP(0, s2, s3, s4, s5, s6, s7);        // u=2
        STEP(1, s3, s4, s5, s6, s7, s0);        // u=3
        BURST(s2, s3);                          // cols +10,+11 (used u=5,6)
        STEP(0, s4, s5, s6, s7, s0, s1);        // u=4
        STEP(1, s5, s6, s7, s0, s1, s2);        // u=5
        BURST(s4, s5);                          // cols +12,+13 (used u=7,8)
        STEP(0, s6, s7, s0, s1, s2, s3);        // u=6
        STEP(1, s7, s0, s1, s2, s3, s4);        // u=7
    }
#undef STEP
#undef DIFF
#undef BURST

#pragma unroll
    for (int i = 0; i < 6; i++)
        atomicMin(&best[(y0 + i) * W48 + xC], bst[i]);
}

// ---------------------------------------------------------------------------
// gather: decode best[p]; gather center pixel of (t+1) patch; write output
// frame + next carry + per-element sq-error.
// ---------------------------------------------------------------------------
__global__ __launch_bounds__(256) void gather_kernel(
    const unsigned long long* __restrict__ best,
    const float4* __restrict__ rec4, const float* __restrict__ x,
    const float* __restrict__ walls,
    float4* __restrict__ curnext, float* __restrict__ dout,
    float* __restrict__ err, int step)
{
    int p = blockIdx.x * 256 + threadIdx.x;
    if (p >= HW) return;
    unsigned int m = (unsigned int)best[p];
    int t = m / HW, q = m % HW;
    float4 v = rec4[(t + 1) * HW + q];
    curnext[p] = v;
    dout[(step + 1) * 3 * HW + 0 * HW + p] = v.x;
    dout[(step + 1) * 3 * HW + 1 * HW + p] = v.y;
    dout[(step + 1) * 3 * HW + 2 * HW + p] = v.z;
    float t0 = x[((step + 1) * 3 + 0) * HW + p];
    float t1 = x[((step + 1) * 3 + 1) * HW + p];
    float t2 = x[((step + 1) * 3 + 2) * HW + p];
    float t3 = walls[p];
    float e = (v.x - t0) * (v.x - t0) + (v.y - t1) * (v.y - t1) +
              (v.z - t2) * (v.z - t2) + (v.w - t3) * (v.w - t3);
    err[step * HW + p] = e;
}

// ---------------------------------------------------------------------------
// loss: deterministic reduction; loss = total / 18432.
// ---------------------------------------------------------------------------
__global__ __launch_bounds__(256) void loss_kernel(
    const float* __restrict__ err, float* __restrict__ dout)
{
    __shared__ float ssum[256];
    float s = 0.f;
    for (int i = threadIdx.x; i < 2 * HW; i += 256) s += err[i];
    ssum[threadIdx.x] = s;
    __syncthreads();
    for (int w = 128; w > 0; w >>= 1) {
        if (threadIdx.x < w) ssum[threadIdx.x] += ssum[threadIdx.x + w];
        __syncthreads();
    }
    if (threadIdx.x == 0) dout[9 * HW] = ssum[0] / 18432.0f;
}

extern "C" void kernel_launch(void* const* d_in, const int* in_sizes, int n_in,
                              void* d_out, int out_size, void* d_ws,
                              size_t ws_size, hipStream_t stream)
{
    const float* x     = (const float*)d_in[0];
    const float* rec   = (const float*)d_in[1];
    const float* walls = (const float*)d_in[2];
    float* dout = (float*)d_out;

    char* ws = (char*)d_ws;
    float4* rec4 = (float4*)ws;                               // 589824 B
    float4* curb = (float4*)(ws + 589824);                    // 110592 B
    float*  err  = (float*)(ws + 589824 + 110592);            //  18432 B
    unsigned long long* best =
        (unsigned long long*)(ws + 589824 + 110592 + 18432);  //  18432 B

    prep_kernel<<<144, 256, 0, stream>>>(x, rec, walls, rec4, curb, dout);
    for (int step = 0; step < 2; step++) {
        hipMemsetAsync(best, 0xFF, (size_t)HW * 8, stream);
        dist_kernel<<<15 * W48, 384, 0, stream>>>(rec4, curb + step * HW, best);
        gather_kernel<<<9, 256, 0, stream>>>(best, rec4, x, walls,
                                             curb + (step + 1) * HW, dout, err,
                                             step);
    }
    loss_kernel<<<1, 256, 0, stream>>>(err, dout);
}